// Round 10
// baseline (90.100 us; speedup 1.0000x reference)
//
#include <hip/hip_runtime.h>
#include <math.h>

// Tropical min-max matmul: out[b,o] = min_i max(x[b,i], w[i,o])
// B=1024, I=512, O=512, fp32.
//
// Round 10: single direct kernel, NO workspace, NO second dispatch.
//  Rationale: all split-K-via-d_ws variants (R2/R4/R9) plateau at total
//  83.7-86.9 regardless of structure — the harness's 268MB d_ws poison
//  fill leaves ~40us of dirty-line HBM writeback draining during our
//  kernels; the 16MB partial write + 16MB read queues behind it. A direct
//  kernel touches only 3MB in / 2MB out.
//  Fixes vs R1 (same 32x64 geometry, measured 44us):
//   - 512 blocks = 2 blocks/CU = 8 waves/CU (R1: 1 wave/SIMD, latency-dead)
//   - all LDS reads b128 (R1: scalar x reads); conflict audit: xf 8-way
//     broadcast conflict-free, wf 16 distinct quads + 4-way broadcast,
//     staging <=2-way (free per m136)
//   - min3 fusion: 1.5 VALU inst/update (VALU floor 5.1us)
//   - BK=64 slabs, next slab prefetched into registers before barrier
//  LDS-pipe floor: (1/2 + 1/4) floats/update * 268M * 4B ~ 805MB / 52TB/s
//  ~ 15.4us -> LDS-bound; expect ~18-24us wall.

#define XSTR 68   // 64 + 4 pad (17 quads, odd -> spreads banks)

__device__ __forceinline__ float4 vmax4(float s, float4 v) {
    return make_float4(fmaxf(s, v.x), fmaxf(s, v.y), fmaxf(s, v.z), fmaxf(s, v.w));
}
__device__ __forceinline__ float4 vmin3(float4 a, float4 b, float4 c) {
    // fmin(fmin(a,b),c) -> v_min3_f32
    return make_float4(fminf(fminf(a.x, b.x), c.x),
                       fminf(fminf(a.y, b.y), c.y),
                       fminf(fminf(a.z, b.z), c.z),
                       fminf(fminf(a.w, b.w), c.w));
}

__global__ __launch_bounds__(256, 2) void minmax_direct(
    const float* __restrict__ x,    // [1024, 512]
    const float* __restrict__ w,    // [512, 512]
    float* __restrict__ out)        // [1024, 512]
{
    __shared__ float xs[32 * XSTR];   //  8704 B  [row][k]
    __shared__ float ws[64 * XSTR];   // 17408 B  [k][col]

    const int t  = threadIdx.x;
    const int tx = t & 15;            // col group: cols tx*4..+3
    const int ty = t >> 4;            // rows ty and ty+16

    const int o0 = blockIdx.x * 64;   // 8 col tiles
    const int b0 = blockIdx.y * 32;   // 32 row tiles

    // staging maps (f4 units)
    const int xrow = t >> 4;          // 0..15 (+16 on i=1), 16 f4 per row
    const int xc4  = (t & 15) * 4;    // k-quad
    const int wk   = t >> 4;          // k rows 0..15 (+16,+32,+48)
    const int wc4  = (t & 15) * 4;    // col quad

    float4 acc[2] = {
        make_float4(INFINITY, INFINITY, INFINITY, INFINITY),
        make_float4(INFINITY, INFINITY, INFINITY, INFINITY)
    };

    // prefetch slab 0
    float4 xg[2], wg[4];
#pragma unroll
    for (int i = 0; i < 2; ++i)
        xg[i] = *(const float4*)(x + (size_t)(b0 + xrow + 16 * i) * 512 + xc4);
#pragma unroll
    for (int i = 0; i < 4; ++i)
        wg[i] = *(const float4*)(w + (size_t)(wk + 16 * i) * 512 + o0 + wc4);

    for (int s = 0; s < 8; ++s) {
        __syncthreads();   // previous slab's LDS reads complete
#pragma unroll
        for (int i = 0; i < 2; ++i)
            *(float4*)(xs + (xrow + 16 * i) * XSTR + xc4) = xg[i];
#pragma unroll
        for (int i = 0; i < 4; ++i)
            *(float4*)(ws + (wk + 16 * i) * XSTR + wc4) = wg[i];
        __syncthreads();

        if (s < 7) {   // prefetch next slab while computing this one
            const int kb = (s + 1) * 64;
#pragma unroll
            for (int i = 0; i < 2; ++i)
                xg[i] = *(const float4*)(x + (size_t)(b0 + xrow + 16 * i) * 512 + kb + xc4);
#pragma unroll
            for (int i = 0; i < 4; ++i)
                wg[i] = *(const float4*)(w + (size_t)(kb + wk + 16 * i) * 512 + o0 + wc4);
        }

#pragma unroll
        for (int k4 = 0; k4 < 16; ++k4) {
            float4 xf[2];
            xf[0] = *(const float4*)(xs + ty * XSTR + 4 * k4);
            xf[1] = *(const float4*)(xs + (ty + 16) * XSTR + 4 * k4);
            float4 wf[4];
#pragma unroll
            for (int j = 0; j < 4; ++j)
                wf[j] = *(const float4*)(ws + (4 * k4 + j) * XSTR + tx * 4);
#pragma unroll
            for (int r = 0; r < 2; ++r) {
                float4 a = acc[r];
                a = vmin3(a, vmax4(xf[r].x, wf[0]), vmax4(xf[r].y, wf[1]));
                a = vmin3(a, vmax4(xf[r].z, wf[2]), vmax4(xf[r].w, wf[3]));
                acc[r] = a;
            }
        }
    }

#pragma unroll
    for (int r = 0; r < 2; ++r)
        *(float4*)(out + (size_t)(b0 + ty + 16 * r) * 512 + o0 + tx * 4) = acc[r];
}

extern "C" void kernel_launch(void* const* d_in, const int* in_sizes, int n_in,
                              void* d_out, int out_size, void* d_ws, size_t ws_size,
                              hipStream_t stream) {
    const float* x = (const float*)d_in[0];   // [1024, 512]
    const float* w = (const float*)d_in[1];   // [512, 512]
    float* out = (float*)d_out;               // [1024, 512]

    minmax_direct<<<dim3(8, 32), 256, 0, stream>>>(x, w, out);
}

// Round 11
// 82.676 us; speedup vs baseline: 1.0898x; 1.0898x over previous
//
#include <hip/hip_runtime.h>
#include <math.h>

// Tropical min-max matmul: out[b,o] = min_i max(x[b,i], w[i,o])
// B=1024, I=512, O=512, fp32.
//
// Round 11 = Round 9 (best measured total) + ONE change: the partial
// buffer handoff uses nontemporal stores/loads. Theory: R9's reduce read
// 16MB of partials left DIRTY in 8 different XCDs' L2s (cross-XCD snoop
// path, ~500GB/s class per R8's counters). `nt` makes partial stores
// bypass L2 into the memory-side (XCD-shared) Infinity Cache/HBM, so the
// reduce's reads are clean high-BW hits from any XCD.
//  - part: 128x128 tile, 8x8/thread, 512-thread blocks = two 256-thread
//    k-groups (K=64/block, intra-block LDS combine), grid 256, split-K=8.
//  - reduce: grid 128, tile=id%32, 8-way min over nt-loaded partials.
//  - All LDS patterns measured conflict-free in R7/R9 (SQ_LDS_BANK_CONFLICT=0).

typedef float v4f __attribute__((ext_vector_type(4)));

__device__ __forceinline__ float4 vmax4(float s, float4 v) {
    return make_float4(fmaxf(s, v.x), fmaxf(s, v.y), fmaxf(s, v.z), fmaxf(s, v.w));
}
__device__ __forceinline__ float4 vmin3(float4 a, float4 b, float4 c) {
    return make_float4(fminf(fminf(a.x, b.x), c.x),
                       fminf(fminf(a.y, b.y), c.y),
                       fminf(fminf(a.z, b.z), c.z),
                       fminf(fminf(a.w, b.w), c.w));
}
__device__ __forceinline__ float4 vmin2(float4 a, float4 b) {
    return make_float4(fminf(a.x, b.x), fminf(a.y, b.y),
                       fminf(a.z, b.z), fminf(a.w, b.w));
}
__device__ __forceinline__ void nt_store4(float* p, float4 v) {
    __builtin_nontemporal_store(*(v4f*)&v, (v4f*)p);
}
__device__ __forceinline__ float4 nt_load4(const float* p) {
    v4f v = __builtin_nontemporal_load((const v4f*)p);
    return *(float4*)&v;
}

__global__ __launch_bounds__(512, 2) void minmax_part(
    const float* __restrict__ x,    // [1024, 512]
    const float* __restrict__ w,    // [512, 512]
    float* __restrict__ part)       // [32 tiles][8 z][128][128] = 16 MB
{
    __shared__ float lds[17408];    // 69632 B union
    float* xs  = lds;               // [128][68] staging
    float* wsh = lds + 8704;        // [64][128] staging

    const int t    = threadIdx.x;   // 0..511
    const int id   = blockIdx.x;    // 0..255
    const int tile = id & 31;       // XCD = id%8 = tile%8 (round-robin)
    const int z    = id >> 5;       // 0..7
    const int o0   = (tile & 3) * 128;
    const int b0   = (tile >> 2) * 128;
    const int kb   = z * 64;

    const int g  = t >> 8;          // k-group 0/1
    const int t2 = t & 255;
    const int tx = t2 & 15;         // cols tx*4..+3 and 64+tx*4..+3
    const int ty = t2 >> 4;         // rows ty+16r, r=0..7

    // ---- stage x[128][64] and w[64][128] once, all 512 threads ----
#pragma unroll
    for (int i = 0; i < 4; ++i) {
        const int f = i * 512 + t;              // 0..2047
        const int row = f >> 4, c4 = (f & 15) * 4;
        *(float4*)(xs + row * 68 + c4) =
            *(const float4*)(x + (size_t)(b0 + row) * 512 + kb + c4);
    }
#pragma unroll
    for (int i = 0; i < 4; ++i) {
        const int f = i * 512 + t;
        const int k = f >> 5, c4 = (f & 31) * 4;
        *(float4*)(wsh + k * 128 + c4) =
            *(const float4*)(w + (size_t)(kb + k) * 512 + o0 + c4);
    }
    __syncthreads();

    float4 acc[8][2];
#pragma unroll
    for (int r = 0; r < 8; ++r)
#pragma unroll
        for (int q = 0; q < 2; ++q)
            acc[r][q] = make_float4(INFINITY, INFINITY, INFINITY, INFINITY);

    const float* xg = xs + g * 32;          // this group's k-offset
    const float* wg = wsh + g * 32 * 128;

#pragma unroll
    for (int k4 = 0; k4 < 8; ++k4) {
        float4 xf[8];
#pragma unroll
        for (int r = 0; r < 8; ++r)
            xf[r] = *(const float4*)(xg + (ty + 16 * r) * 68 + 4 * k4);
        float4 wf[4][2];
#pragma unroll
        for (int j = 0; j < 4; ++j)
#pragma unroll
            for (int q = 0; q < 2; ++q)
                wf[j][q] = *(const float4*)(wg + (4 * k4 + j) * 128 + tx * 4 + 64 * q);
#pragma unroll
        for (int r = 0; r < 8; ++r) {
#pragma unroll
            for (int q = 0; q < 2; ++q) {
                float4 a = acc[r][q];
                a = vmin3(a, vmax4(xf[r].x, wf[0][q]), vmax4(xf[r].y, wf[1][q]));
                a = vmin3(a, vmax4(xf[r].z, wf[2][q]), vmax4(xf[r].w, wf[3][q]));
                acc[r][q] = a;
            }
        }
    }

    // ---- intra-block combine: group 1 -> LDS, group 0 mins & nt-stores ----
    __syncthreads();                 // staging reads done; safe to reuse lds
    if (g == 1) {
        float* s = lds + t2 * 68;    // stride 17 quads -> <=2-way (free)
#pragma unroll
        for (int r = 0; r < 8; ++r)
#pragma unroll
            for (int q = 0; q < 2; ++q)
                *(float4*)(s + (r * 2 + q) * 4) = acc[r][q];
    }
    __syncthreads();
    if (g == 0) {
        const float* s = lds + t2 * 68;
        float* pt = part + ((size_t)tile * 8 + z) * 16384;
#pragma unroll
        for (int r = 0; r < 8; ++r)
#pragma unroll
            for (int q = 0; q < 2; ++q) {
                const float4 o = vmin2(acc[r][q], *(const float4*)(s + (r * 2 + q) * 4));
                nt_store4(pt + (ty + 16 * r) * 128 + tx * 4 + 64 * q, o);
            }
    }
}

// grid 128: tile = id%32 (same XCD as producers), quarter = id/32.
__global__ __launch_bounds__(256) void minmax_reduce(
    const float* __restrict__ part, float4* __restrict__ out)
{
    const int t    = threadIdx.x;
    const int id   = blockIdx.x;
    const int tile = id & 31;
    const int qt   = id >> 5;            // 0..3
    const int oc4  = (tile & 3) * 32;    // f4 col offset
    const int b0   = (tile >> 2) * 128;

    const float* pp = part + (size_t)tile * 8 * 16384;
#pragma unroll
    for (int i = 0; i < 4; ++i) {
        const int c = qt * 1024 + i * 256 + t;   // f4 cell 0..4095
        float4 v = nt_load4(pp + c * 4);
#pragma unroll
        for (int z = 1; z < 8; ++z)
            v = vmin2(v, nt_load4(pp + (z * 4096 + c) * 4));
        const int row = c >> 5, cc = c & 31;
        out[(size_t)(b0 + row) * 128 + oc4 + cc] = v;
    }
}

// fallback (ws too small): direct, no split-K, correct but slower
__global__ __launch_bounds__(256) void minmax_direct(
    const float* __restrict__ x, const float* __restrict__ w,
    float* __restrict__ out)
{
    __shared__ float xs[128 * 36];
    __shared__ float wsh[32 * 128];
    const int t = threadIdx.x, tx = t & 15, ty = t >> 4;
    const int o0 = blockIdx.x * 128, b0 = blockIdx.y * 128;
    float4 acc[8][2];
#pragma unroll
    for (int r = 0; r < 8; ++r)
#pragma unroll
        for (int q = 0; q < 2; ++q)
            acc[r][q] = make_float4(INFINITY, INFINITY, INFINITY, INFINITY);
    for (int s = 0; s < 16; ++s) {
        const int kb = s * 32;
        __syncthreads();
#pragma unroll
        for (int i = 0; i < 4; ++i) {
            const int f = i * 256 + t;
            const int row = f >> 3, c4 = (f & 7) * 4;
            *(float4*)(xs + row * 36 + c4) =
                *(const float4*)(x + (size_t)(b0 + row) * 512 + kb + c4);
        }
#pragma unroll
        for (int i = 0; i < 4; ++i) {
            const int f = i * 256 + t;
            const int k = f >> 5, c4 = (f & 31) * 4;
            *(float4*)(wsh + k * 128 + c4) =
                *(const float4*)(w + (size_t)(kb + k) * 512 + o0 + c4);
        }
        __syncthreads();
#pragma unroll
        for (int k4 = 0; k4 < 8; ++k4) {
            float4 xf[8];
#pragma unroll
            for (int r = 0; r < 8; ++r)
                xf[r] = *(const float4*)(xs + (ty + 16 * r) * 36 + 4 * k4);
            float4 wf[4][2];
#pragma unroll
            for (int j = 0; j < 4; ++j)
#pragma unroll
                for (int q = 0; q < 2; ++q)
                    wf[j][q] = *(const float4*)(wsh + (4 * k4 + j) * 128 + tx * 4 + 64 * q);
#pragma unroll
            for (int r = 0; r < 8; ++r)
#pragma unroll
                for (int q = 0; q < 2; ++q) {
                    float4 a = acc[r][q];
                    a = vmin3(a, vmax4(xf[r].x, wf[0][q]), vmax4(xf[r].y, wf[1][q]));
                    a = vmin3(a, vmax4(xf[r].z, wf[2][q]), vmax4(xf[r].w, wf[3][q]));
                    acc[r][q] = a;
                }
        }
    }
#pragma unroll
    for (int r = 0; r < 8; ++r)
#pragma unroll
        for (int q = 0; q < 2; ++q)
            *(float4*)(out + (size_t)(b0 + ty + 16 * r) * 512 + o0 + tx * 4 + 64 * q) = acc[r][q];
}

extern "C" void kernel_launch(void* const* d_in, const int* in_sizes, int n_in,
                              void* d_out, int out_size, void* d_ws, size_t ws_size,
                              hipStream_t stream) {
    const float* x = (const float*)d_in[0];   // [1024, 512]
    const float* w = (const float*)d_in[1];   // [512, 512]
    float* out = (float*)d_out;               // [1024, 512]

    const size_t part_bytes = 16ull * 1024 * 1024;   // 32 tiles * 8 z * 64KB
    if (ws_size >= part_bytes) {
        float* part = (float*)d_ws;
        minmax_part<<<dim3(256), 512, 0, stream>>>(x, w, part);
        minmax_reduce<<<dim3(128), 256, 0, stream>>>((const float*)part, (float4*)out);
    } else {
        minmax_direct<<<dim3(4, 8), 256, 0, stream>>>(x, w, out);
    }
}

// Round 13
// 79.389 us; speedup vs baseline: 1.1349x; 1.0414x over previous
//
#include <hip/hip_runtime.h>
#include <math.h>

// Tropical min-max matmul: out[b,o] = min_i max(x[b,i], w[i,o])
// B=1024, I=512, O=512, fp32.
//
// Round 13 = Round 12 with the w-staging bug fixed: R12's map staged only
// cols 0..31 of the 64-wide w slab (4KB of 8KB); wf reads at tx>=8 hit
// uninitialized LDS -> absmax 0.146. New map: each thread stores rows
// wk, wk+16 at col quad (t2&15) -> full 32x64 slab, <=2-way bank aliasing.
//
// Architecture (unchanged from R12):
//  - SINGLE dispatch, no workspace (2-kernel d_ws family floor ~83-85us:
//    ~49us harness + 2x ~10us dispatch + exec).
//  - grid 256 (32x64 tile), 512 thr = two 256-thr k-groups (k-halves),
//    8 waves/CU, thread tile 2x4.
//  - w in LDS (reg-prefetched slabs); x direct from global (4 unique
//    16B addrs/wave = TA broadcast, L1-hot). Pipes/CU: LDS ~10us,
//    VALU ~5us, L1 ~7us, overlapped across 8 waves.
//  - min3 fusion 1.5 inst/update; intra-block combine via LDS; g0 stores.

#define WSTR 68   // 68-float row stride (17 quads)

__device__ __forceinline__ float4 vmax4(float s, float4 v) {
    return make_float4(fmaxf(s, v.x), fmaxf(s, v.y), fmaxf(s, v.z), fmaxf(s, v.w));
}
__device__ __forceinline__ float4 vmin3(float4 a, float4 b, float4 c) {
    // fmin(fmin(a,b),c) -> v_min3_f32
    return make_float4(fminf(fminf(a.x, b.x), c.x),
                       fminf(fminf(a.y, b.y), c.y),
                       fminf(fminf(a.z, b.z), c.z),
                       fminf(fminf(a.w, b.w), c.w));
}
__device__ __forceinline__ float4 vmin2(float4 a, float4 b) {
    return make_float4(fminf(a.x, b.x), fminf(a.y, b.y),
                       fminf(a.z, b.z), fminf(a.w, b.w));
}

__global__ __launch_bounds__(512, 1) void minmax_one(
    const float* __restrict__ x,    // [1024, 512]
    const float* __restrict__ w,    // [512, 512]
    float* __restrict__ out)        // [1024, 512]
{
    __shared__ float wsh[2][32 * WSTR];   // per-group w slab, 17408 B
    __shared__ float scr[256 * 12];       // combine scratch, 12288 B

    const int t  = threadIdx.x;     // 0..511
    const int g  = t >> 8;          // k-group: g0 -> k in [0,256), g1 -> [256,512)
    const int t2 = t & 255;
    const int tx = t2 & 15;         // cols tx*4..+3
    const int ty = t2 >> 4;         // rows ty and ty+16

    const int o0 = blockIdx.x * 64;
    const int r0 = blockIdx.y * 32;
    const int kg = g * 256;

    // w staging map: 2 float4/thread per 32-k slab (rows wk, wk+16; full 64 cols)
    const int wk = t2 >> 4;         // 0..15
    const int wc = (t2 & 15) * 4;   // 0..60

    const float* xr0 = x + (size_t)(r0 + ty) * 512 + kg;
    const float* xr1 = x + (size_t)(r0 + ty + 16) * 512 + kg;

    float4 acc0 = make_float4(INFINITY, INFINITY, INFINITY, INFINITY);
    float4 acc1 = make_float4(INFINITY, INFINITY, INFINITY, INFINITY);

    // prefetch slab 0 of this group's w window
    float4 wpre0 = *(const float4*)(w + (size_t)(kg + wk) * 512 + o0 + wc);
    float4 wpre1 = *(const float4*)(w + (size_t)(kg + wk + 16) * 512 + o0 + wc);

    for (int s = 0; s < 8; ++s) {
        __syncthreads();   // previous slab's LDS reads complete
        *(float4*)(&wsh[g][wk * WSTR + wc])        = wpre0;
        *(float4*)(&wsh[g][(wk + 16) * WSTR + wc]) = wpre1;
        __syncthreads();
        if (s < 7) {
            const int kb = kg + (s + 1) * 32;
            wpre0 = *(const float4*)(w + (size_t)(kb + wk) * 512 + o0 + wc);
            wpre1 = *(const float4*)(w + (size_t)(kb + wk + 16) * 512 + o0 + wc);
        }

        const int ks = s * 32;
#pragma unroll
        for (int k4 = 0; k4 < 8; ++k4) {
            // x from global: 4 unique addrs/wave (16-lane broadcast), L1-hot
            const float4 xf0 = *(const float4*)(xr0 + ks + 4 * k4);
            const float4 xf1 = *(const float4*)(xr1 + ks + 4 * k4);
            float4 wf[4];
#pragma unroll
            for (int j = 0; j < 4; ++j)
                wf[j] = *(const float4*)(&wsh[g][(4 * k4 + j) * WSTR + tx * 4]);

            acc0 = vmin3(acc0, vmax4(xf0.x, wf[0]), vmax4(xf0.y, wf[1]));
            acc0 = vmin3(acc0, vmax4(xf0.z, wf[2]), vmax4(xf0.w, wf[3]));
            acc1 = vmin3(acc1, vmax4(xf1.x, wf[0]), vmax4(xf1.y, wf[1]));
            acc1 = vmin3(acc1, vmax4(xf1.z, wf[2]), vmax4(xf1.w, wf[3]));
        }
    }

    // ---- cross-group combine (intra-block, no fences) ----
    __syncthreads();
    if (g == 1) {
        *(float4*)(&scr[t2 * 12])     = acc0;
        *(float4*)(&scr[t2 * 12 + 4]) = acc1;
    }
    __syncthreads();
    if (g == 0) {
        const float4 p0 = *(const float4*)(&scr[t2 * 12]);
        const float4 p1 = *(const float4*)(&scr[t2 * 12 + 4]);
        const float4 out0 = vmin2(acc0, p0);
        const float4 out1 = vmin2(acc1, p1);
        *(float4*)(out + (size_t)(r0 + ty) * 512 + o0 + tx * 4)      = out0;
        *(float4*)(out + (size_t)(r0 + ty + 16) * 512 + o0 + tx * 4) = out1;
    }
}

extern "C" void kernel_launch(void* const* d_in, const int* in_sizes, int n_in,
                              void* d_out, int out_size, void* d_ws, size_t ws_size,
                              hipStream_t stream) {
    const float* x = (const float*)d_in[0];   // [1024, 512]
    const float* w = (const float*)d_in[1];   // [512, 512]
    float* out = (float*)d_out;               // [1024, 512]

    minmax_one<<<dim3(8, 32), 512, 0, stream>>>(x, w, out);
}